// Round 1
// baseline (453.982 us; speedup 1.0000x reference)
//
#include <hip/hip_runtime.h>
#include <cmath>

#define BATCH 128
#define HDIM 1024
#define KDIM 1024
#define VOCAB 32001
#define G3 3072

typedef __bf16 bf16_t;
typedef bf16_t bf16x8 __attribute__((ext_vector_type(8)));
typedef float f32x4 __attribute__((ext_vector_type(4)));

// Load 8 consecutive fp32 (32B-aligned) and convert to bf16x8 (RNE via HW cvt)
__device__ __forceinline__ bf16x8 cvt_frag(const float* __restrict__ p) {
    const f32x4* q = (const f32x4*)p;
    f32x4 u = q[0];
    f32x4 v = q[1];
    bf16x8 r;
    r[0] = (bf16_t)u[0]; r[1] = (bf16_t)u[1]; r[2] = (bf16_t)u[2]; r[3] = (bf16_t)u[3];
    r[4] = (bf16_t)v[0]; r[5] = (bf16_t)v[1]; r[6] = (bf16_t)v[2]; r[7] = (bf16_t)v[3];
    return r;
}

// C[M,N] = A[M,K=1024] * W[N,K=1024]^T + bias[N], bf16 MFMA, fp32 accumulate.
// Wave tile: (16*MFRAG) M x (16*NFRAG) N. Block = 4 waves side-by-side in N.
template<int MFRAG, int NFRAG>
__device__ __forceinline__ void gemm_core(const float* __restrict__ A,
                                          const float* __restrict__ W,
                                          const float* __restrict__ bias,
                                          float* __restrict__ C,
                                          int N, int bx, int by) {
    const int wave = threadIdx.x >> 6;
    const int lane = threadIdx.x & 63;
    const int l15  = lane & 15;
    const int quad = lane >> 4;
    const int n0 = (bx * 4 + wave) * (16 * NFRAG);
    const int m0 = by * (16 * MFRAG);
    const int kb = quad * 8;

    f32x4 acc[MFRAG][NFRAG];
#pragma unroll
    for (int i = 0; i < MFRAG; ++i)
#pragma unroll
        for (int j = 0; j < NFRAG; ++j)
            acc[i][j] = f32x4{0.f, 0.f, 0.f, 0.f};

    const float* arow[MFRAG];
#pragma unroll
    for (int i = 0; i < MFRAG; ++i)
        arow[i] = A + (size_t)(m0 + i * 16 + l15) * KDIM + kb;

    const float* wrow[NFRAG];
#pragma unroll
    for (int j = 0; j < NFRAG; ++j) {
        int r = n0 + j * 16 + l15;
        if (r > N - 1) r = N - 1;   // clamp OOB rows; store is guarded below
        wrow[j] = W + (size_t)r * KDIM + kb;
    }

    for (int k0 = 0; k0 < KDIM; k0 += 32) {
        bf16x8 bfrag[NFRAG];
#pragma unroll
        for (int j = 0; j < NFRAG; ++j) bfrag[j] = cvt_frag(wrow[j] + k0);
        bf16x8 afrag[MFRAG];
#pragma unroll
        for (int i = 0; i < MFRAG; ++i) afrag[i] = cvt_frag(arow[i] + k0);
#pragma unroll
        for (int i = 0; i < MFRAG; ++i)
#pragma unroll
            for (int j = 0; j < NFRAG; ++j)
                acc[i][j] = __builtin_amdgcn_mfma_f32_16x16x32_bf16(
                    afrag[i], bfrag[j], acc[i][j], 0, 0, 0);
    }

#pragma unroll
    for (int j = 0; j < NFRAG; ++j) {
        int col = n0 + j * 16 + l15;
        if (col < N) {
            float bv = bias[col];
#pragma unroll
            for (int i = 0; i < MFRAG; ++i) {
#pragma unroll
                for (int r = 0; r < 4; ++r) {
                    int row = m0 + i * 16 + quad * 4 + r;
                    C[(size_t)row * N + col] = acc[i][j][r] + bv;
                }
            }
        }
    }
}

template<int MFRAG, int NFRAG>
__global__ __launch_bounds__(256) void gemm_single(const float* __restrict__ A,
                                                   const float* __restrict__ W,
                                                   const float* __restrict__ bias,
                                                   float* __restrict__ C, int N) {
    gemm_core<MFRAG, NFRAG>(A, W, bias, C, N, blockIdx.x, blockIdx.y);
}

// Two GEMMs (x*W_ih^T and h*W_hh^T) in one launch, selected by blockIdx.z
template<int MFRAG, int NFRAG>
__global__ __launch_bounds__(256) void gemm_dual(const float* __restrict__ A0,
                                                 const float* __restrict__ W0,
                                                 const float* __restrict__ b0,
                                                 float* __restrict__ C0,
                                                 const float* __restrict__ A1,
                                                 const float* __restrict__ W1,
                                                 const float* __restrict__ b1,
                                                 float* __restrict__ C1, int N) {
    if (blockIdx.z == 0)
        gemm_core<MFRAG, NFRAG>(A0, W0, b0, C0, N, blockIdx.x, blockIdx.y);
    else
        gemm_core<MFRAG, NFRAG>(A1, W1, b1, C1, N, blockIdx.x, blockIdx.y);
}

__global__ __launch_bounds__(256) void embed_relu(const int* __restrict__ idx,
                                                  const float* __restrict__ emb,
                                                  float* __restrict__ x) {
    int i = blockIdx.x * 256 + threadIdx.x;   // 0 .. 131071
    int b = i >> 10, e = i & 1023;
    float v = emb[(size_t)idx[b] * HDIM + e];
    x[i] = fmaxf(v, 0.f);
}

// PyTorch GRU gate math: gates ordered (r, z, n) along the 3H axis
__global__ __launch_bounds__(256) void gru_gate(const float* __restrict__ gi,
                                                const float* __restrict__ gh,
                                                const float* __restrict__ hprev,
                                                float* __restrict__ hout) {
    int i = blockIdx.x * 256 + threadIdx.x;   // 0 .. 131071
    int b = i >> 10, j = i & 1023;
    size_t base = (size_t)b * G3 + j;
    float ir = gi[base], iz = gi[base + 1024], inn = gi[base + 2048];
    float hr = gh[base], hz = gh[base + 1024], hn  = gh[base + 2048];
    float r = 1.f / (1.f + expf(-(ir + hr)));
    float z = 1.f / (1.f + expf(-(iz + hz)));
    float n = tanhf(inn + r * hn);
    hout[i] = (1.f - z) * n + z * hprev[i];
}

__global__ __launch_bounds__(256) void log_softmax_rows(float* __restrict__ out) {
    int b = blockIdx.x;
    float* row = out + (size_t)b * VOCAB;
    __shared__ float smax[4];
    __shared__ float ssum[4];

    float m = -3.4e38f;
    for (int i = threadIdx.x; i < VOCAB; i += 256) m = fmaxf(m, row[i]);
#pragma unroll
    for (int o = 32; o; o >>= 1) m = fmaxf(m, __shfl_down(m, o));
    if ((threadIdx.x & 63) == 0) smax[threadIdx.x >> 6] = m;
    __syncthreads();
    float M = fmaxf(fmaxf(smax[0], smax[1]), fmaxf(smax[2], smax[3]));

    float s = 0.f;
    for (int i = threadIdx.x; i < VOCAB; i += 256) s += expf(row[i] - M);
#pragma unroll
    for (int o = 32; o; o >>= 1) s += __shfl_down(s, o);
    if ((threadIdx.x & 63) == 0) ssum[threadIdx.x >> 6] = s;
    __syncthreads();
    float L = M + logf(ssum[0] + ssum[1] + ssum[2] + ssum[3]);

    for (int i = threadIdx.x; i < VOCAB; i += 256) row[i] = row[i] - L;
}

extern "C" void kernel_launch(void* const* d_in, const int* in_sizes, int n_in,
                              void* d_out, int out_size, void* d_ws, size_t ws_size,
                              hipStream_t stream) {
    const int*   ivec  = (const int*)  d_in[0];
    const float* hidden= (const float*)d_in[1];
    const float* emb   = (const float*)d_in[2];
    const float* w_ih0 = (const float*)d_in[3];
    const float* w_hh0 = (const float*)d_in[4];
    const float* b_ih0 = (const float*)d_in[5];
    const float* b_hh0 = (const float*)d_in[6];
    const float* w_ih1 = (const float*)d_in[7];
    const float* w_hh1 = (const float*)d_in[8];
    const float* b_ih1 = (const float*)d_in[9];
    const float* b_hh1 = (const float*)d_in[10];
    const float* w_out = (const float*)d_in[11];
    const float* b_out = (const float*)d_in[12];

    float* out = (float*)d_out;
    float* h0  = out + (size_t)BATCH * VOCAB;          // hidden_out[0]
    float* h1  = h0 + BATCH * HDIM;                    // hidden_out[1]

    // Scratch inside the logits region (fully overwritten by the final GEMM):
    float* x  = out;            // [128,1024]
    float* gi = out + 131072;   // [128,3072]
    float* gh = out + 524288;   // [128,3072]

    const float* hprev0 = hidden;
    const float* hprev1 = hidden + BATCH * HDIM;

    embed_relu<<<512, 256, 0, stream>>>(ivec, emb, x);

    // Layer 0: gi = x*w_ih0^T + b_ih0 ; gh = h_prev0*w_hh0^T + b_hh0
    gemm_dual<2, 2><<<dim3(24, 4, 2), 256, 0, stream>>>(
        x, w_ih0, b_ih0, gi, hprev0, w_hh0, b_hh0, gh, G3);
    gru_gate<<<512, 256, 0, stream>>>(gi, gh, hprev0, h0);

    // Layer 1
    gemm_dual<2, 2><<<dim3(24, 4, 2), 256, 0, stream>>>(
        h0, w_ih1, b_ih1, gi, hprev1, w_hh1, b_hh1, gh, G3);
    gru_gate<<<512, 256, 0, stream>>>(gi, gh, hprev1, h1);

    // Vocab projection: wave tile 128M x 32N so w_out streams once from HBM
    gemm_single<8, 2><<<dim3(251, 1, 1), 256, 0, stream>>>(h1, w_out, b_out, out, VOCAB);

    log_softmax_rows<<<128, 256, 0, stream>>>(out);
}

// Round 2
// 349.205 us; speedup vs baseline: 1.3000x; 1.3000x over previous
//
#include <hip/hip_runtime.h>
#include <cmath>

#define BATCH 128
#define KDIM 1024
#define VOCAB 32001
#define G3 3072
#define GIP_STRIDE (BATCH * G3)   // 393216 floats per split-partial

typedef __bf16 bf16_t;
typedef bf16_t bf16x8 __attribute__((ext_vector_type(8)));
typedef float f32x4 __attribute__((ext_vector_type(4)));

// ---------------- async global->LDS (16B per lane, wave-uniform LDS base) ----
__device__ __forceinline__ void stage16(const float* g, void* lds_wave_base) {
    __builtin_amdgcn_global_load_lds(
        (const __attribute__((address_space(1))) void*)g,
        (__attribute__((address_space(3))) void*)lds_wave_base, 16, 0, 0);
}

// Read one MFMA A/B fragment (8 bf16 along K) from an LDS fp32 tile [rows][32],
// granule-XOR-swizzled: physical granule = logical ^ (row&7).
__device__ __forceinline__ bf16x8 frag_from_lds(const float* s, int row, int quad) {
    const int s7 = row & 7;
    const f32x4 u = *(const f32x4*)(s + row * 32 + (((2 * quad) ^ s7) * 4));
    const f32x4 v = *(const f32x4*)(s + row * 32 + (((2 * quad + 1) ^ s7) * 4));
    bf16x8 r;
    r[0] = (bf16_t)u[0]; r[1] = (bf16_t)u[1]; r[2] = (bf16_t)u[2]; r[3] = (bf16_t)u[3];
    r[4] = (bf16_t)v[0]; r[5] = (bf16_t)v[1]; r[6] = (bf16_t)v[2]; r[7] = (bf16_t)v[3];
    return r;
}

// ---------------- staged GEMM core: C[m0:m0+BM, n0:n0+64] += A*W^T -----------
// A [M,1024], W [Wrows,1024] both row-major fp32. 256 threads = 4 waves;
// wave w computes cols n0+16w..+15, all BM rows (MFRAG = BM/16).
template<int BM, bool BIAS>
__device__ __forceinline__ void gemm_staged_core(
    const float* __restrict__ A, const float* __restrict__ W,
    float* __restrict__ C, const float* __restrict__ bias,
    int ldc, int Wrows, int m0, int n0, int kbeg, int kend)
{
    __shared__ float sA[BM * 32];
    __shared__ float sB[64 * 32];
    const int t    = threadIdx.x;
    const int wave = t >> 6;
    const int lane = t & 63;
    const int l15  = lane & 15;
    const int quad = lane >> 4;
    // staging coords: each thread copies 16B of row `srow` (granule sg, swizzled)
    const int srow = t >> 3;   // 0..31 per round
    const int sg   = t & 7;

    constexpr int MFRAG = BM / 16;
    f32x4 acc[MFRAG];
#pragma unroll
    for (int i = 0; i < MFRAG; ++i) acc[i] = f32x4{0.f, 0.f, 0.f, 0.f};

    for (int k0 = kbeg; k0 < kend; k0 += 32) {
#pragma unroll
        for (int r = 0; r < BM / 32; ++r) {
            const int row = r * 32 + srow;
            const int kg  = sg ^ (row & 7);
            stage16(A + (size_t)(m0 + row) * KDIM + k0 + kg * 4,
                    (char*)sA + r * 4096 + wave * 1024);
        }
#pragma unroll
        for (int r = 0; r < 2; ++r) {
            const int row = r * 32 + srow;
            int wr = n0 + row; if (wr > Wrows - 1) wr = Wrows - 1;
            const int kg = sg ^ (row & 7);
            stage16(W + (size_t)wr * KDIM + k0 + kg * 4,
                    (char*)sB + r * 4096 + wave * 1024);
        }
        __syncthreads();   // drains vmcnt -> LDS tiles visible
        const bf16x8 bf = frag_from_lds(sB, wave * 16 + l15, quad);
#pragma unroll
        for (int i = 0; i < MFRAG; ++i) {
            const bf16x8 af = frag_from_lds(sA, i * 16 + l15, quad);
            acc[i] = __builtin_amdgcn_mfma_f32_16x16x32_bf16(af, bf, acc[i], 0, 0, 0);
        }
        __syncthreads();   // before next-stage overwrite
    }

    const int col = n0 + wave * 16 + l15;
    if (col < Wrows) {
        const float bv = BIAS ? bias[col] : 0.f;
#pragma unroll
        for (int i = 0; i < MFRAG; ++i)
#pragma unroll
            for (int r = 0; r < 4; ++r) {
                const int row = m0 + i * 16 + quad * 4 + r;
                C[(size_t)row * ldc + col] = acc[i][r] + bv;
            }
    }
}

// Vocab projection: grid (2 m-tiles, 501 n-tiles); m-tiles adjacent for L3 reuse
__global__ __launch_bounds__(256) void gemm_vocab(const float* __restrict__ A,
                                                  const float* __restrict__ W,
                                                  const float* __restrict__ bias,
                                                  float* __restrict__ C) {
    gemm_staged_core<64, true>(A, W, C, bias, VOCAB, VOCAB,
                               blockIdx.x * 64, blockIdx.y * 64, 0, KDIM);
}

// GRU dual GEMM, split-K=4 into fp32 partials: giP/ghP [4][128][3072]
__global__ __launch_bounds__(256) void gemm_gru(const float* __restrict__ x,
                                                const float* __restrict__ wih,
                                                float* __restrict__ giP,
                                                const float* __restrict__ h,
                                                const float* __restrict__ whh,
                                                float* __restrict__ ghP) {
    const int m0    = (blockIdx.x & 1) * 64;
    const int split = blockIdx.x >> 1;
    const int n0    = blockIdx.y * 64;
    const float* A; const float* W; float* C;
    if (blockIdx.z == 0) { A = x; W = wih; C = giP; }
    else                 { A = h; W = whh; C = ghP; }
    C += (size_t)split * GIP_STRIDE;
    gemm_staged_core<64, false>(A, W, C, nullptr, G3, G3, m0, n0,
                                split * 256, split * 256 + 256);
}

// ---------------- embed + relu (float4) --------------------------------------
__global__ __launch_bounds__(256) void embed_relu(const int* __restrict__ idx,
                                                  const float* __restrict__ emb,
                                                  float* __restrict__ x) {
    const int i  = blockIdx.x * 256 + threadIdx.x;  // 0..32767 float4 groups
    const int b  = i >> 8;
    const int e4 = i & 255;
    const f32x4 v = ((const f32x4*)(emb + (size_t)idx[b] * KDIM))[e4];
    f32x4 o;
#pragma unroll
    for (int k = 0; k < 4; ++k) o[k] = fmaxf(v[k], 0.f);
    ((f32x4*)x)[i] = o;
}

// ---------------- gate: sum 4 split-K partials + biases + GRU math -----------
__device__ __forceinline__ f32x4 sum_splits(const float* p) {
    f32x4 s = *(const f32x4*)p;
    s += *(const f32x4*)(p + GIP_STRIDE);
    s += *(const f32x4*)(p + 2 * GIP_STRIDE);
    s += *(const f32x4*)(p + 3 * GIP_STRIDE);
    return s;
}

__global__ __launch_bounds__(256) void gru_gate(const float* __restrict__ giP,
                                                const float* __restrict__ ghP,
                                                const float* __restrict__ b_ih,
                                                const float* __restrict__ b_hh,
                                                const float* __restrict__ hprev,
                                                float* __restrict__ hout) {
    const int i  = blockIdx.x * 256 + threadIdx.x;  // 0..32767
    const int b  = i >> 8;
    const int j  = (i & 255) * 4;
    const size_t base = (size_t)b * G3 + j;

    f32x4 ir = sum_splits(giP + base),        hr = sum_splits(ghP + base);
    f32x4 iz = sum_splits(giP + base + 1024), hz = sum_splits(ghP + base + 1024);
    f32x4 in = sum_splits(giP + base + 2048), hn = sum_splits(ghP + base + 2048);
    const f32x4 bir = *(const f32x4*)(b_ih + j);
    const f32x4 biz = *(const f32x4*)(b_ih + j + 1024);
    const f32x4 bin = *(const f32x4*)(b_ih + j + 2048);
    const f32x4 bhr = *(const f32x4*)(b_hh + j);
    const f32x4 bhz = *(const f32x4*)(b_hh + j + 1024);
    const f32x4 bhn = *(const f32x4*)(b_hh + j + 2048);
    const f32x4 hp  = *(const f32x4*)(hprev + (size_t)b * KDIM + j);

    f32x4 o;
#pragma unroll
    for (int k = 0; k < 4; ++k) {
        const float r = 1.f / (1.f + __expf(-(ir[k] + bir[k] + hr[k] + bhr[k])));
        const float z = 1.f / (1.f + __expf(-(iz[k] + biz[k] + hz[k] + bhz[k])));
        const float a = in[k] + bin[k] + r * (hn[k] + bhn[k]);
        const float n = 1.f - 2.f / (__expf(2.f * a) + 1.f);   // tanh
        o[k] = (1.f - z) * n + z * hp[k];
    }
    *(f32x4*)(hout + (size_t)b * KDIM + j) = o;
}

// ---------------- online log-softmax: one read pass (m,s), one write pass ----
__global__ __launch_bounds__(1024) void log_softmax_rows(float* __restrict__ out) {
    float* row = out + (size_t)blockIdx.x * VOCAB;
    const int t = threadIdx.x;
    __shared__ float sm[16], ss[16];

    float m = -3.4e38f, s = 0.f;
    for (int i = t; i < VOCAB; i += 1024) {
        const float v  = row[i];
        const float mn = fmaxf(m, v);
        s = s * __expf(m - mn) + __expf(v - mn);
        m = mn;
    }
#pragma unroll
    for (int o = 32; o; o >>= 1) {
        const float mo = __shfl_down(m, o);
        const float so = __shfl_down(s, o);
        const float mn = fmaxf(m, mo);
        s = s * __expf(m - mn) + so * __expf(mo - mn);
        m = mn;
    }
    if ((t & 63) == 0) { sm[t >> 6] = m; ss[t >> 6] = s; }
    __syncthreads();
    if (t == 0) {
        float M = sm[0], S = ss[0];
#pragma unroll
        for (int w = 1; w < 16; ++w) {
            const float mn = fmaxf(M, sm[w]);
            S = S * __expf(M - mn) + ss[w] * __expf(sm[w] - mn);
            M = mn;
        }
        sm[0] = M + __logf(S);
    }
    __syncthreads();
    const float L = sm[0];

    for (int i = t * 4; i + 3 < VOCAB; i += 4096) {
        f32x4 v = *(const f32x4*)(row + i);
        v[0] -= L; v[1] -= L; v[2] -= L; v[3] -= L;
        *(f32x4*)(row + i) = v;
    }
    if (t == 0) row[32000] -= L;
}

// ---------------- launch -----------------------------------------------------
extern "C" void kernel_launch(void* const* d_in, const int* in_sizes, int n_in,
                              void* d_out, int out_size, void* d_ws, size_t ws_size,
                              hipStream_t stream) {
    const int*   ivec  = (const int*)  d_in[0];
    const float* hidden= (const float*)d_in[1];
    const float* emb   = (const float*)d_in[2];
    const float* w_ih0 = (const float*)d_in[3];
    const float* w_hh0 = (const float*)d_in[4];
    const float* b_ih0 = (const float*)d_in[5];
    const float* b_hh0 = (const float*)d_in[6];
    const float* w_ih1 = (const float*)d_in[7];
    const float* w_hh1 = (const float*)d_in[8];
    const float* b_ih1 = (const float*)d_in[9];
    const float* b_hh1 = (const float*)d_in[10];
    const float* w_out = (const float*)d_in[11];
    const float* b_out = (const float*)d_in[12];

    float* out = (float*)d_out;
    float* h0  = out + (size_t)BATCH * VOCAB;   // hidden_out[0]
    float* h1  = h0 + BATCH * KDIM;             // hidden_out[1]

    // Scratch inside logits region (fully overwritten by vocab GEMM):
    float* x   = out;                           // [128,1024]            131072
    float* giP = out + 131072;                  // [4][128][3072]       1572864
    float* ghP = giP + 4 * GIP_STRIDE;          // [4][128][3072]       1572864
                                                // total 3276800 < 4096128 ok

    const float* hprev0 = hidden;
    const float* hprev1 = hidden + BATCH * KDIM;

    embed_relu<<<128, 256, 0, stream>>>(ivec, emb, x);

    gemm_gru<<<dim3(8, 48, 2), 256, 0, stream>>>(x, w_ih0, giP, hprev0, w_hh0, ghP);
    gru_gate<<<128, 256, 0, stream>>>(giP, ghP, b_ih0, b_hh0, hprev0, h0);

    gemm_gru<<<dim3(8, 48, 2), 256, 0, stream>>>(h0, w_ih1, giP, hprev1, w_hh1, ghP);
    gru_gate<<<128, 256, 0, stream>>>(giP, ghP, b_ih1, b_hh1, hprev1, h1);

    gemm_vocab<<<dim3(2, 501), 256, 0, stream>>>(h1, w_out, b_out, out);

    log_softmax_rows<<<128, 1024, 0, stream>>>(out);
}